// Round 5
// baseline (426.659 us; speedup 1.0000x reference)
//
#include <hip/hip_runtime.h>
#include <stdint.h>

typedef short bf16x8 __attribute__((ext_vector_type(8)));
typedef float f32x4 __attribute__((ext_vector_type(4)));

__device__ __forceinline__ unsigned short f2bf(float f) {
    union { float f; unsigned int u; } x; x.f = f;
    unsigned int r = x.u + 0x7FFFu + ((x.u >> 16) & 1u);
    return (unsigned short)(r >> 16);
}

// ---- weight prep: f32 [K][N] row-major -> bf16 transposed [N][K] in ws ----
__global__ void prep_weights(const float* __restrict__ w1e, const float* __restrict__ w2e,
                             const float* __restrict__ w1n, const float* __restrict__ w2n,
                             unsigned short* __restrict__ ws) {
    int idx = blockIdx.x * 256 + threadIdx.x;
    if (idx < 32768) {
        int n = idx >> 8, k = idx & 255;
        ws[idx] = f2bf(w1e[k * 128 + n]);
    } else if (idx < 49152) {
        int t = idx - 32768; int n = t >> 7, k = t & 127;
        ws[idx] = f2bf(w2e[k * 128 + n]);
    } else if (idx < 81920) {
        int t = idx - 49152; int n = t >> 8, k = t & 255;
        ws[idx] = f2bf(w1n[k * 128 + n]);
    } else if (idx < 98304) {
        int t = idx - 81920; int n = t >> 7, k = t & 127;
        ws[idx] = f2bf(w2n[k * 128 + n]);
    }
}

// ---- standalone gather-mean: one wave per row, f32 sum -> bf16 mean ----
// Numerically identical to the fused X staging (f32 accumulate, *1/16, f2bf).
// Zero LDS, low VGPR -> max occupancy, ~16 independent 512B row-reads in
// flight per wave.
__global__ __launch_bounds__(256)
void gather_mean(int rows,
                 const float* __restrict__ src,    // [*][128] f32 table
                 const int*   __restrict__ idx,    // [rows][16]
                 unsigned short* __restrict__ out) // [rows][128] bf16 mean
{
    const int wid  = threadIdx.x >> 6;
    const int lane = threadIdx.x & 63;
    const int c0   = 2 * lane;
    const int step = gridDim.x * 4;
    for (int row = blockIdx.x * 4 + wid; row < rows; row += step) {
        const int* nb = idx + (size_t)row * 16;
        const int4 i0 = *(const int4*)(nb);
        const int4 i1 = *(const int4*)(nb + 4);
        const int4 i2 = *(const int4*)(nb + 8);
        const int4 i3 = *(const int4*)(nb + 12);
        const int js[16] = { i0.x, i0.y, i0.z, i0.w, i1.x, i1.y, i1.z, i1.w,
                             i2.x, i2.y, i2.z, i2.w, i3.x, i3.y, i3.z, i3.w };
        float ax = 0.f, ay = 0.f;
        #pragma unroll
        for (int k = 0; k < 16; ++k) {
            const float2 u = *(const float2*)(src + (size_t)js[k] * 128 + c0);
            ax += u.x; ay += u.y;
        }
        const unsigned int p = (unsigned int)f2bf(ax * 0.0625f)
                             | ((unsigned int)f2bf(ay * 0.0625f) << 16);
        *(unsigned int*)(out + (size_t)row * 128 + c0) = p;
    }
}

// ---- streaming fused GEMM1+relu -> GEMM2+relu -> LN (no gather) ----
// LDS phases alias one 33792-B block (barriers between):
//   A: X [64][256] bf16 swizzled (byte ^= (row&7)<<4)   32768 B
//   B: Y [64][128] bf16 swizzled                         16384 B
//   C: O [64][132] f32                                   33792 B
__global__ __launch_bounds__(256, 4)
void cagnn_gemm(int rows,
                const float* __restrict__ self_feats,    // [rows][128] f32
                const unsigned short* __restrict__ mean16,// [rows][128] bf16
                const unsigned short* __restrict__ w1t,  // [128][256] bf16 (n-major)
                const unsigned short* __restrict__ w2t,  // [128][128] bf16 (n-major)
                const float* __restrict__ b1,
                const float* __restrict__ b2,
                const float* __restrict__ gamma,
                const float* __restrict__ beta,
                float* __restrict__ out)                 // [rows][128] f32
{
    __shared__ __align__(16) char lds[33792];
    float* O = (float*)lds;
    char*  Ybase = lds;

    const int tid  = threadIdx.x;
    const int wid  = tid >> 6;
    const int lane = tid & 63;
    const int base = blockIdx.x * 64;

    // ---------- phase A: stage X = [self | mean16] ----------
    {
        const int c0 = 2 * lane;
        for (int rr = wid; rr < 64; rr += 4) {
            const int row = base + rr;
            float sx = 0.f, sy = 0.f;
            unsigned int pm = 0;
            if (row < rows) {
                const float2 v = *(const float2*)(self_feats + (size_t)row * 128 + c0);
                sx = v.x; sy = v.y;
                pm = *(const unsigned int*)(mean16 + (size_t)row * 128 + c0);
            }
            const unsigned int ps = (unsigned int)f2bf(sx) | ((unsigned int)f2bf(sy) << 16);
            const int bs = (rr * 512 + c0 * 2) ^ ((rr & 7) << 4);
            const int bm = (rr * 512 + (128 + c0) * 2) ^ ((rr & 7) << 4);
            *(unsigned int*)(lds + bs) = ps;
            *(unsigned int*)(lds + bm) = pm;
        }
    }

    const int n0 = wid * 32;
    const int bn = lane & 15;
    const int kg = lane >> 4;

    // preload B1 fragments (before barrier; held in regs)
    bf16x8 B1[8][2];
    #pragma unroll
    for (int ks = 0; ks < 8; ++ks)
        #pragma unroll
        for (int nt = 0; nt < 2; ++nt)
            B1[ks][nt] = *(const bf16x8*)(w1t + (n0 + nt * 16 + bn) * 256 + ks * 32 + kg * 8);

    __syncthreads();   // b1: X ready

    // ---------- GEMM1: [64,256] @ [256,128] ----------
    f32x4 acc[4][2];
    #pragma unroll
    for (int m = 0; m < 4; ++m)
        #pragma unroll
        for (int nt = 0; nt < 2; ++nt)
            acc[m][nt] = (f32x4){0.f, 0.f, 0.f, 0.f};

    #pragma unroll
    for (int ks = 0; ks < 8; ++ks) {
        bf16x8 a[4];
        #pragma unroll
        for (int m = 0; m < 4; ++m) {
            const int row = m * 16 + bn;
            const int byte = (row * 512 + ks * 64 + kg * 16) ^ ((row & 7) << 4);
            a[m] = *(const bf16x8*)(lds + byte);
        }
        #pragma unroll
        for (int m = 0; m < 4; ++m)
            #pragma unroll
            for (int nt = 0; nt < 2; ++nt)
                acc[m][nt] = __builtin_amdgcn_mfma_f32_16x16x32_bf16(a[m], B1[ks][nt], acc[m][nt], 0, 0, 0);
    }

    // preload B2 fragments
    bf16x8 B2[4][2];
    #pragma unroll
    for (int ks = 0; ks < 4; ++ks)
        #pragma unroll
        for (int nt = 0; nt < 2; ++nt)
            B2[ks][nt] = *(const bf16x8*)(w2t + (n0 + nt * 16 + bn) * 128 + ks * 32 + kg * 8);

    __syncthreads();   // b2: X reads done -> Y may overwrite

    // ---------- bias1 + relu -> Y ----------
    float b1v[2] = { b1[n0 + bn], b1[n0 + 16 + bn] };
    #pragma unroll
    for (int m = 0; m < 4; ++m)
        #pragma unroll
        for (int nt = 0; nt < 2; ++nt)
            #pragma unroll
            for (int j = 0; j < 4; ++j) {
                const int row = m * 16 + kg * 4 + j;
                const int col = n0 + nt * 16 + bn;
                float v = fmaxf(acc[m][nt][j] + b1v[nt], 0.f);
                const int byte = (row * 256 + col * 2) ^ ((row & 7) << 4);
                *(unsigned short*)(Ybase + byte) = f2bf(v);
            }

    __syncthreads();   // b3: Y ready

    // ---------- GEMM2: [64,128] @ [128,128] ----------
    f32x4 acc2[4][2];
    #pragma unroll
    for (int m = 0; m < 4; ++m)
        #pragma unroll
        for (int nt = 0; nt < 2; ++nt)
            acc2[m][nt] = (f32x4){0.f, 0.f, 0.f, 0.f};

    #pragma unroll
    for (int ks = 0; ks < 4; ++ks) {
        bf16x8 a[4];
        #pragma unroll
        for (int m = 0; m < 4; ++m) {
            const int row = m * 16 + bn;
            const int byte = (row * 256 + ks * 64 + kg * 16) ^ ((row & 7) << 4);
            a[m] = *(const bf16x8*)(Ybase + byte);
        }
        #pragma unroll
        for (int m = 0; m < 4; ++m)
            #pragma unroll
            for (int nt = 0; nt < 2; ++nt)
                acc2[m][nt] = __builtin_amdgcn_mfma_f32_16x16x32_bf16(a[m], B2[ks][nt], acc2[m][nt], 0, 0, 0);
    }

    __syncthreads();   // b4: Y reads done -> O may overwrite

    // ---------- bias2 + relu -> O ----------
    float b2v[2] = { b2[n0 + bn], b2[n0 + 16 + bn] };
    #pragma unroll
    for (int m = 0; m < 4; ++m)
        #pragma unroll
        for (int nt = 0; nt < 2; ++nt)
            #pragma unroll
            for (int j = 0; j < 4; ++j) {
                const int row = m * 16 + kg * 4 + j;
                const int col = n0 + nt * 16 + bn;
                O[row * 132 + col] = fmaxf(acc2[m][nt][j] + b2v[nt], 0.f);
            }

    __syncthreads();   // b5: O ready

    // ---------- LayerNorm + writeout ----------
    {
        const int r    = tid >> 2;
        const int part = tid & 3;
        const float* Or = O + r * 132 + part * 32;
        float sum = 0.f, sq = 0.f;
        #pragma unroll
        for (int c = 0; c < 32; c += 4) {
            float4 v = *(const float4*)(Or + c);
            sum += v.x + v.y + v.z + v.w;
            sq  += v.x * v.x + v.y * v.y + v.z * v.z + v.w * v.w;
        }
        sum += __shfl_xor(sum, 1); sq += __shfl_xor(sq, 1);
        sum += __shfl_xor(sum, 2); sq += __shfl_xor(sq, 2);
        const float mean = sum * (1.f / 128.f);
        const float var  = sq * (1.f / 128.f) - mean * mean;
        const float rstd = rsqrtf(var + 1e-5f);
        const int row = base + r;
        if (row < rows) {
            float* op = out + (size_t)row * 128 + part * 32;
            const float* gp = gamma + part * 32;
            const float* bp = beta + part * 32;
            #pragma unroll
            for (int c = 0; c < 32; c += 4) {
                float4 v = *(const float4*)(Or + c);
                float4 g = *(const float4*)(gp + c);
                float4 b = *(const float4*)(bp + c);
                float4 o;
                o.x = (v.x - mean) * rstd * g.x + b.x;
                o.y = (v.y - mean) * rstd * g.y + b.y;
                o.z = (v.z - mean) * rstd * g.z + b.z;
                o.w = (v.w - mean) * rstd * g.w + b.w;
                *(float4*)(op + c) = o;
            }
        }
    }
}

extern "C" void kernel_launch(void* const* d_in, const int* in_sizes, int n_in,
                              void* d_out, int out_size, void* d_ws, size_t ws_size,
                              hipStream_t stream) {
    const int*   node_neighbors = (const int*)d_in[0];
    const int*   edge_neighbors = (const int*)d_in[1];
    const float* node_feats     = (const float*)d_in[2];
    const float* edge_feats     = (const float*)d_in[3];
    const float* W_edge_agg     = (const float*)d_in[4];
    const float* b_edge_agg     = (const float*)d_in[5];
    const float* W_edge_com     = (const float*)d_in[6];
    const float* b_edge_com     = (const float*)d_in[7];
    const float* W_node_agg     = (const float*)d_in[8];
    const float* b_node_agg     = (const float*)d_in[9];
    const float* W_node_com     = (const float*)d_in[10];
    const float* b_node_com     = (const float*)d_in[11];
    const float* ln_gamma       = (const float*)d_in[12];
    const float* ln_beta        = (const float*)d_in[13];

    const int N = in_sizes[2] / 128;   // 50000
    const int E = in_sizes[3] / 128;   // 100000

    float* out_nodes = (float*)d_out;
    float* out_edges = (float*)d_out + (size_t)N * 128;

    unsigned short* wsu    = (unsigned short*)d_ws;
    unsigned short* mean_e = wsu + 98304;                  // [E][128] bf16
    unsigned short* mean_n = mean_e + (size_t)E * 128;     // [N][128] bf16
    // ws need = (98304 + E*128 + N*128) * 2 B  ~= 38.6 MB; round-2 run proved
    // ws_size >= 51.4 MB on this harness.

    prep_weights<<<384, 256, 0, stream>>>(W_edge_agg, W_edge_com, W_node_agg, W_node_com, wsu);

    // --- edge path ---
    gather_mean<<<2048, 256, 0, stream>>>(E, edge_feats, edge_neighbors, mean_e);
    cagnn_gemm<<<(E + 63) / 64, 256, 0, stream>>>(
        E, edge_feats, mean_e,
        wsu + 0, wsu + 32768, b_edge_agg, b_edge_com, ln_gamma, ln_beta, out_edges);

    // --- node path (gathers from new edge feats in d_out) ---
    gather_mean<<<2048, 256, 0, stream>>>(N, out_edges, node_neighbors, mean_n);
    cagnn_gemm<<<(N + 63) / 64, 256, 0, stream>>>(
        N, node_feats, mean_n,
        wsu + 49152, wsu + 81920, b_node_agg, b_node_com, ln_gamma, ln_beta, out_nodes);
}

// Round 6
// 404.318 us; speedup vs baseline: 1.0553x; 1.0553x over previous
//
#include <hip/hip_runtime.h>
#include <stdint.h>

typedef short bf16x8 __attribute__((ext_vector_type(8)));
typedef float f32x4 __attribute__((ext_vector_type(4)));

__device__ __forceinline__ unsigned short f2bf(float f) {
    union { float f; unsigned int u; } x; x.f = f;
    unsigned int r = x.u + 0x7FFFu + ((x.u >> 16) & 1u);
    return (unsigned short)(r >> 16);
}

// ---- weight prep: f32 [K][N] row-major -> bf16 transposed [N][K] in ws ----
__global__ void prep_weights(const float* __restrict__ w1e, const float* __restrict__ w2e,
                             const float* __restrict__ w1n, const float* __restrict__ w2n,
                             unsigned short* __restrict__ ws) {
    int idx = blockIdx.x * 256 + threadIdx.x;
    if (idx < 32768) {
        int n = idx >> 8, k = idx & 255;
        ws[idx] = f2bf(w1e[k * 128 + n]);
    } else if (idx < 49152) {
        int t = idx - 32768; int n = t >> 7, k = t & 127;
        ws[idx] = f2bf(w2e[k * 128 + n]);
    } else if (idx < 81920) {
        int t = idx - 49152; int n = t >> 8, k = t & 255;
        ws[idx] = f2bf(w1n[k * 128 + n]);
    } else if (idx < 98304) {
        int t = idx - 81920; int n = t >> 7, k = t & 127;
        ws[idx] = f2bf(w2n[k * 128 + n]);
    }
}

// ---- standalone gather-mean, v2: half-wave per row, float4 lanes ----
// Each 32-lane half covers a full 512-B row with float4 loads; a wave works
// 2 rows concurrently; all 16 neighbor loads per row issue back-to-back
// (~16 KB in flight per wave, 2x the float2 version). f32 accumulate, *1/16,
// f2bf — numerically identical to the fused X staging.
__global__ __launch_bounds__(256)
void gather_mean(int rows,
                 const float* __restrict__ src,    // [*][128] f32 table
                 const int*   __restrict__ idx,    // [rows][16]
                 unsigned short* __restrict__ out) // [rows][128] bf16 mean
{
    const int tid  = threadIdx.x;
    const int wid  = tid >> 6;
    const int lane = tid & 63;
    const int half = lane >> 5;   // which row of the wave's pair
    const int l32  = lane & 31;
    const int c4   = 4 * l32;     // float4 col base
    const int step = gridDim.x * 8;   // 4 waves * 2 rows per block
    for (int row = (blockIdx.x * 4 + wid) * 2 + half; row < rows; row += step) {
        const int* nb = idx + (size_t)row * 16;
        const int4 i0 = *(const int4*)(nb);
        const int4 i1 = *(const int4*)(nb + 4);
        const int4 i2 = *(const int4*)(nb + 8);
        const int4 i3 = *(const int4*)(nb + 12);
        const int js[16] = { i0.x, i0.y, i0.z, i0.w, i1.x, i1.y, i1.z, i1.w,
                             i2.x, i2.y, i2.z, i2.w, i3.x, i3.y, i3.z, i3.w };
        f32x4 a = (f32x4){0.f, 0.f, 0.f, 0.f};
        f32x4 b = (f32x4){0.f, 0.f, 0.f, 0.f};
        #pragma unroll
        for (int k = 0; k < 16; k += 2) {
            const f32x4 u = *(const f32x4*)(src + (size_t)js[k] * 128 + c4);
            const f32x4 v = *(const f32x4*)(src + (size_t)js[k + 1] * 128 + c4);
            a += u;
            b += v;
        }
        a += b;
        uint2 p;
        p.x = (unsigned int)f2bf(a[0] * 0.0625f) | ((unsigned int)f2bf(a[1] * 0.0625f) << 16);
        p.y = (unsigned int)f2bf(a[2] * 0.0625f) | ((unsigned int)f2bf(a[3] * 0.0625f) << 16);
        *(uint2*)(out + (size_t)row * 128 + c4) = p;
    }
}

// ---- streaming fused GEMM1+relu -> GEMM2+relu -> LN (no gather) ----
// LDS phases alias one 33792-B block (barriers between):
//   A: X [64][256] bf16 swizzled (byte ^= (row&7)<<4)   32768 B
//   B: Y [64][128] bf16 swizzled                         16384 B
//   C: O [64][132] f32                                   33792 B
__global__ __launch_bounds__(256, 4)
void cagnn_gemm(int rows,
                const float* __restrict__ self_feats,    // [rows][128] f32
                const unsigned short* __restrict__ mean16,// [rows][128] bf16
                const unsigned short* __restrict__ w1t,  // [128][256] bf16 (n-major)
                const unsigned short* __restrict__ w2t,  // [128][128] bf16 (n-major)
                const float* __restrict__ b1,
                const float* __restrict__ b2,
                const float* __restrict__ gamma,
                const float* __restrict__ beta,
                float* __restrict__ out)                 // [rows][128] f32
{
    __shared__ __align__(16) char lds[33792];
    float* O = (float*)lds;
    char*  Ybase = lds;

    const int tid  = threadIdx.x;
    const int wid  = tid >> 6;
    const int lane = tid & 63;
    const int base = blockIdx.x * 64;

    // ---------- phase A: stage X = [self | mean16] ----------
    {
        const int c0 = 2 * lane;
        for (int rr = wid; rr < 64; rr += 4) {
            const int row = base + rr;
            float sx = 0.f, sy = 0.f;
            unsigned int pm = 0;
            if (row < rows) {
                const float2 v = *(const float2*)(self_feats + (size_t)row * 128 + c0);
                sx = v.x; sy = v.y;
                pm = *(const unsigned int*)(mean16 + (size_t)row * 128 + c0);
            }
            const unsigned int ps = (unsigned int)f2bf(sx) | ((unsigned int)f2bf(sy) << 16);
            const int bs = (rr * 512 + c0 * 2) ^ ((rr & 7) << 4);
            const int bm = (rr * 512 + (128 + c0) * 2) ^ ((rr & 7) << 4);
            *(unsigned int*)(lds + bs) = ps;
            *(unsigned int*)(lds + bm) = pm;
        }
    }

    const int n0 = wid * 32;
    const int bn = lane & 15;
    const int kg = lane >> 4;

    // preload B1 fragments (before barrier; held in regs)
    bf16x8 B1[8][2];
    #pragma unroll
    for (int ks = 0; ks < 8; ++ks)
        #pragma unroll
        for (int nt = 0; nt < 2; ++nt)
            B1[ks][nt] = *(const bf16x8*)(w1t + (n0 + nt * 16 + bn) * 256 + ks * 32 + kg * 8);

    __syncthreads();   // b1: X ready

    // ---------- GEMM1: [64,256] @ [256,128] ----------
    f32x4 acc[4][2];
    #pragma unroll
    for (int m = 0; m < 4; ++m)
        #pragma unroll
        for (int nt = 0; nt < 2; ++nt)
            acc[m][nt] = (f32x4){0.f, 0.f, 0.f, 0.f};

    #pragma unroll
    for (int ks = 0; ks < 8; ++ks) {
        bf16x8 a[4];
        #pragma unroll
        for (int m = 0; m < 4; ++m) {
            const int row = m * 16 + bn;
            const int byte = (row * 512 + ks * 64 + kg * 16) ^ ((row & 7) << 4);
            a[m] = *(const bf16x8*)(lds + byte);
        }
        #pragma unroll
        for (int m = 0; m < 4; ++m)
            #pragma unroll
            for (int nt = 0; nt < 2; ++nt)
                acc[m][nt] = __builtin_amdgcn_mfma_f32_16x16x32_bf16(a[m], B1[ks][nt], acc[m][nt], 0, 0, 0);
    }

    // preload B2 fragments
    bf16x8 B2[4][2];
    #pragma unroll
    for (int ks = 0; ks < 4; ++ks)
        #pragma unroll
        for (int nt = 0; nt < 2; ++nt)
            B2[ks][nt] = *(const bf16x8*)(w2t + (n0 + nt * 16 + bn) * 128 + ks * 32 + kg * 8);

    __syncthreads();   // b2: X reads done -> Y may overwrite

    // ---------- bias1 + relu -> Y ----------
    float b1v[2] = { b1[n0 + bn], b1[n0 + 16 + bn] };
    #pragma unroll
    for (int m = 0; m < 4; ++m)
        #pragma unroll
        for (int nt = 0; nt < 2; ++nt)
            #pragma unroll
            for (int j = 0; j < 4; ++j) {
                const int row = m * 16 + kg * 4 + j;
                const int col = n0 + nt * 16 + bn;
                float v = fmaxf(acc[m][nt][j] + b1v[nt], 0.f);
                const int byte = (row * 256 + col * 2) ^ ((row & 7) << 4);
                *(unsigned short*)(Ybase + byte) = f2bf(v);
            }

    __syncthreads();   // b3: Y ready

    // ---------- GEMM2: [64,128] @ [128,128] ----------
    f32x4 acc2[4][2];
    #pragma unroll
    for (int m = 0; m < 4; ++m)
        #pragma unroll
        for (int nt = 0; nt < 2; ++nt)
            acc2[m][nt] = (f32x4){0.f, 0.f, 0.f, 0.f};

    #pragma unroll
    for (int ks = 0; ks < 4; ++ks) {
        bf16x8 a[4];
        #pragma unroll
        for (int m = 0; m < 4; ++m) {
            const int row = m * 16 + bn;
            const int byte = (row * 256 + ks * 64 + kg * 16) ^ ((row & 7) << 4);
            a[m] = *(const bf16x8*)(Ybase + byte);
        }
        #pragma unroll
        for (int m = 0; m < 4; ++m)
            #pragma unroll
            for (int nt = 0; nt < 2; ++nt)
                acc2[m][nt] = __builtin_amdgcn_mfma_f32_16x16x32_bf16(a[m], B2[ks][nt], acc2[m][nt], 0, 0, 0);
    }

    __syncthreads();   // b4: Y reads done -> O may overwrite

    // ---------- bias2 + relu -> O ----------
    float b2v[2] = { b2[n0 + bn], b2[n0 + 16 + bn] };
    #pragma unroll
    for (int m = 0; m < 4; ++m)
        #pragma unroll
        for (int nt = 0; nt < 2; ++nt)
            #pragma unroll
            for (int j = 0; j < 4; ++j) {
                const int row = m * 16 + kg * 4 + j;
                const int col = n0 + nt * 16 + bn;
                O[row * 132 + col] = fmaxf(acc2[m][nt][j] + b2v[nt], 0.f);
            }

    __syncthreads();   // b5: O ready

    // ---------- LayerNorm + writeout ----------
    {
        const int r    = tid >> 2;
        const int part = tid & 3;
        const float* Or = O + r * 132 + part * 32;
        float sum = 0.f, sq = 0.f;
        #pragma unroll
        for (int c = 0; c < 32; c += 4) {
            float4 v = *(const float4*)(Or + c);
            sum += v.x + v.y + v.z + v.w;
            sq  += v.x * v.x + v.y * v.y + v.z * v.z + v.w * v.w;
        }
        sum += __shfl_xor(sum, 1); sq += __shfl_xor(sq, 1);
        sum += __shfl_xor(sum, 2); sq += __shfl_xor(sq, 2);
        const float mean = sum * (1.f / 128.f);
        const float var  = sq * (1.f / 128.f) - mean * mean;
        const float rstd = rsqrtf(var + 1e-5f);
        const int row = base + r;
        if (row < rows) {
            float* op = out + (size_t)row * 128 + part * 32;
            const float* gp = gamma + part * 32;
            const float* bp = beta + part * 32;
            #pragma unroll
            for (int c = 0; c < 32; c += 4) {
                float4 v = *(const float4*)(Or + c);
                float4 g = *(const float4*)(gp + c);
                float4 b = *(const float4*)(bp + c);
                float4 o;
                o.x = (v.x - mean) * rstd * g.x + b.x;
                o.y = (v.y - mean) * rstd * g.y + b.y;
                o.z = (v.z - mean) * rstd * g.z + b.z;
                o.w = (v.w - mean) * rstd * g.w + b.w;
                *(float4*)(op + c) = o;
            }
        }
    }
}

extern "C" void kernel_launch(void* const* d_in, const int* in_sizes, int n_in,
                              void* d_out, int out_size, void* d_ws, size_t ws_size,
                              hipStream_t stream) {
    const int*   node_neighbors = (const int*)d_in[0];
    const int*   edge_neighbors = (const int*)d_in[1];
    const float* node_feats     = (const float*)d_in[2];
    const float* edge_feats     = (const float*)d_in[3];
    const float* W_edge_agg     = (const float*)d_in[4];
    const float* b_edge_agg     = (const float*)d_in[5];
    const float* W_edge_com     = (const float*)d_in[6];
    const float* b_edge_com     = (const float*)d_in[7];
    const float* W_node_agg     = (const float*)d_in[8];
    const float* b_node_agg     = (const float*)d_in[9];
    const float* W_node_com     = (const float*)d_in[10];
    const float* b_node_com     = (const float*)d_in[11];
    const float* ln_gamma       = (const float*)d_in[12];
    const float* ln_beta        = (const float*)d_in[13];

    const int N = in_sizes[2] / 128;   // 50000
    const int E = in_sizes[3] / 128;   // 100000

    float* out_nodes = (float*)d_out;
    float* out_edges = (float*)d_out + (size_t)N * 128;

    unsigned short* wsu    = (unsigned short*)d_ws;
    unsigned short* mean_e = wsu + 98304;                  // [E][128] bf16
    unsigned short* mean_n = mean_e + (size_t)E * 128;     // [N][128] bf16

    prep_weights<<<384, 256, 0, stream>>>(W_edge_agg, W_edge_com, W_node_agg, W_node_com, wsu);

    // --- edge path ---
    gather_mean<<<2048, 256, 0, stream>>>(E, edge_feats, edge_neighbors, mean_e);
    cagnn_gemm<<<(E + 63) / 64, 256, 0, stream>>>(
        E, edge_feats, mean_e,
        wsu + 0, wsu + 32768, b_edge_agg, b_edge_com, ln_gamma, ln_beta, out_edges);

    // --- node path (gathers from new edge feats in d_out) ---
    gather_mean<<<2048, 256, 0, stream>>>(N, out_edges, node_neighbors, mean_n);
    cagnn_gemm<<<(N + 63) / 64, 256, 0, stream>>>(
        N, node_feats, mean_n,
        wsu + 49152, wsu + 81920, b_node_agg, b_node_com, ln_gamma, ln_beta, out_nodes);
}